// Round 14
// baseline (272.419 us; speedup 1.0000x reference)
//
#include <hip/hip_runtime.h>

// ---------------------------------------------------------------------------
// 2-layer LSTM (BN=8192 seqs, T=64, F=16, H=128) + graph mixing stage.
// Round 14 = r11 32x32-MFMA LSTM structure (verified absmax 0.0, low bank
// conflicts) + r13 cell algebra + shared-rcp-across-pair + single prep launch.
// Issue-bound model (r13): step = MFMA-issue + trans-issue + arith ~= 97% of
// measured. 32x32 cuts MFMA issue ~17% (1015 vs 844 FLOP/cyc/SIMD); shared
// rcp cuts trans 28->24 per wave-step.
// Gate packing for 32x32 D layout (col=l&31, row=(r&3)+8*(r>>2)+4*(l>>5)):
//   lane l, reg r holds gate p=r&3 of unit u = 8W + 4*(l>>5) + (r>>2),
//   data-row = l&31. Lane's 4 cells = 4 ADJACENT units -> one b64 write.
// 32x32x16 A/B frag (verified r11):
//   A: lane l holds A[l&31][16*kt + 8*(l>>5)+i]; B: B[16*kt+8*(l>>5)+i][l&31].
// Graph stage: 16x16 (verified rounds 1-13), unchanged.
// ---------------------------------------------------------------------------

typedef __attribute__((ext_vector_type(4))) float f32x4;
typedef __attribute__((ext_vector_type(16))) float f32x16;
typedef __attribute__((ext_vector_type(2))) float f32x2;
typedef __attribute__((ext_vector_type(8))) __bf16 bf16x8;
typedef __attribute__((ext_vector_type(8))) unsigned short u16x8;
typedef __attribute__((ext_vector_type(4))) unsigned short u16x4;

#define DEV static __device__ __forceinline__

DEV unsigned short f2bf(float f) {
  unsigned u = __builtin_bit_cast(unsigned, f);
  u = u + 0x7fffu + ((u >> 16) & 1u);
  return (unsigned short)(u >> 16);
}
DEV float bf2f(unsigned short s) {
  unsigned u = ((unsigned)s) << 16;
  return __builtin_bit_cast(float, u);
}

DEV float fexp2(float x) { return __builtin_amdgcn_exp2f(x); }
DEV f32x2 exp2v2(f32x2 x) { f32x2 r; r[0] = fexp2(x[0]); r[1] = fexp2(x[1]); return r; }

// Two independent LSTM cells in packed f32x2 lanes; 5 exp2 + 1 rcp per cell
// (shared rcp across the pair at both divide sites).
// Gates PRE-SCALED: i,f,o by log2(e); g by 2*log2(e).  cs = 2*log2(e)*c.
DEV unsigned cell_pair(f32x2 gi, f32x2 gf, f32x2 gg, f32x2 go, f32x2& cs) {
  const float K2 = 2.88539008f;
  f32x2 one = {1.f, 1.f};
  f32x2 t1 = exp2v2(gg);                               // e^{2g}
  f32x2 t2 = exp2v2((f32x2){-gi[0], -gi[1]});          // e^{-i}
  f32x2 ef = exp2v2((f32x2){-gf[0], -gf[1]});          // e^{-f}
  f32x2 d1 = t1 + one;
  f32x2 den1 = d1 * t2 + d1;                           // (t1+1)(1+e^{-i})
  f32x2 e1 = one + ef;
  f32x2 num = cs * den1 + (f32x2){K2, K2} * (t1 - one) * e1;
  f32x2 D = e1 * den1;
  float R = __builtin_amdgcn_rcpf(D[0] * D[1]);        // shared rcp
  cs[0] = num[0] * D[1] * R;
  cs[1] = num[1] * D[0] * R;
  f32x2 t3 = exp2v2(cs);                               // e^{2c}
  f32x2 t4 = exp2v2((f32x2){-go[0], -go[1]});          // e^{-o}
  f32x2 d3 = t3 + one;
  f32x2 den3 = d3 * t4 + d3;
  float R3 = __builtin_amdgcn_rcpf(den3[0] * den3[1]); // shared rcp
  float h0 = (t3[0] - 1.f) * den3[1] * R3;
  float h1 = (t3[1] - 1.f) * den3[0] * R3;
  unsigned r;
  asm("v_cvt_pk_bf16_f32 %0, %1, %2" : "=v"(r) : "v"(h0), "v"(h1));
  return r;
}

// ---------------- workspace layout (bytes) ----------------
#define O_W0PK   0            // 16W*10kt*64l*8i bf16 = 163840
#define O_W1PK   163840       // 16W*16kt*64l*8i bf16 = 262144
#define O_APK    425984       // 131072
#define O_W1APK  557056       // 32768
#define O_W2APK  589824       // 32768
#define O_W3APK  622592       // 32768
#define O_BIAS0  655360       // 2048
#define O_BIAS1  657408       // 2048 (pre-scaled)
#define O_HTT    659456       // 2097152  hT^T [32][128][256] bf16
#define O_HAT    2756608      // 2097152
#define O_MIDT   4853760      // 2097152
#define O_W1HAT  6950912      // 2097152
#define O_W3R    9048064      // 2097152
#define O_XPK    11145216     // 33554432 x B-frags 32x32: [rt32][t][2 slice][64 lane]
#define O_H1     44699648     // up to 128 MiB h1 [row][t][128] bf16

#define PREPX_TOT 2097152
#define PREP_TOT  328704
#define PREPALL_TOT (PREPX_TOT + PREP_TOT)

// ---------------- merged prepass: x frags + weight packs -------------------
__global__ void prep_all(const float* __restrict__ x, const float* __restrict__ A,
    const float* __restrict__ Wih0, const float* __restrict__ Whh0,
    const float* __restrict__ bih0, const float* __restrict__ bhh0,
    const float* __restrict__ Wih1, const float* __restrict__ Whh1,
    const float* __restrict__ bih1, const float* __restrict__ bhh1,
    const float* __restrict__ W1, const float* __restrict__ W2,
    const float* __restrict__ W3, char* __restrict__ ws)
{
  const float K1 = 1.44269504f, K2 = 2.88539008f;
  int gidx = blockIdx.x * blockDim.x + threadIdx.x;
  if (gidx < PREPX_TOT) {                  // x -> 32x32 B-frags
    int tid = gidx;
    int lane = tid & 63;
    int slice = (tid >> 6) & 1;
    int t = (tid >> 7) & 63;
    int rt32 = tid >> 13;                       // 0..255
    int col = lane & 31, hi = lane >> 5;
    u16x8 v = (u16x8)0;
    if (slice == 0) {
      const float* p = x + ((long)(rt32 * 32 + col) * 64 + t) * 16 + 8 * hi;
      float4 a = *(const float4*)p;
      float4 b = *(const float4*)(p + 4);
      v[0] = f2bf(a.x); v[1] = f2bf(a.y); v[2] = f2bf(a.z); v[3] = f2bf(a.w);
      v[4] = f2bf(b.x); v[5] = f2bf(b.y); v[6] = f2bf(b.z); v[7] = f2bf(b.w);
    } else if (hi == 0) {
      v[0] = 0x3F80;                            // k=16 -> 1.0f (bias column)
    }
    ((u16x8*)(ws + O_XPK))[tid] = v;
    return;
  }
  int idx = gidx - PREPX_TOT;
  if (idx >= PREP_TOT) return;
  if (idx < 81920) {                       // W0pk 32x32 A-frags: [W][kt0..9]
    int o = idx, i = o & 7, l = (o >> 3) & 63, f = o >> 9;
    int kt = f % 10, W = f / 10;
    int rho = l & 31, hik = l >> 5;
    int p = rho & 3, hi = (rho >> 2) & 1, q = rho >> 3;
    int gc = p * 128 + 8 * W + 4 * hi + q;
    float sc = (p == 2) ? K2 : K1;
    int k = 16 * kt + 8 * hik + i;
    float v;
    if (k < 128) v = Whh0[gc * 128 + k];
    else {
      int kk = k - 128;
      v = (kk < 16) ? Wih0[gc * 16 + kk]
                    : (kk == 16 ? (bih0[gc] + bhh0[gc]) : 0.f);  // bias row
    }
    ((unsigned short*)(ws + O_W0PK))[idx] = f2bf(v * sc);
  } else if (idx < 212992) {               // W1pk: kt<8 = h1-input, kt>=8 = recurrent
    int o = idx - 81920, i = o & 7, l = (o >> 3) & 63, f = o >> 9;
    int kt = f & 15, W = f >> 4;
    int rho = l & 31, hik = l >> 5;
    int p = rho & 3, hi = (rho >> 2) & 1, q = rho >> 3;
    int gc = p * 128 + 8 * W + 4 * hi + q;
    float sc = (p == 2) ? K2 : K1;
    int k = 16 * kt + 8 * hik + i;
    float v = (k < 128) ? Wih1[gc * 128 + k] : Whh1[gc * 128 + (k - 128)];
    ((unsigned short*)(ws + O_W1PK))[o] = f2bf(v * sc);
  } else if (idx < 278528) {               // Apk = sigmoid(A) B-frags (16x16 graph)
    int o = idx - 212992, i = o & 7, l = (o >> 3) & 63, f = o >> 9;
    int kt = f & 7, ct = f >> 3;
    int n = 32 * kt + 8 * (l >> 4) + i;
    int lc = 16 * ct + (l & 15);
    float e = fexp2(-K1 * A[n * 256 + lc]);
    ((unsigned short*)(ws + O_APK))[o] = f2bf(__builtin_amdgcn_rcpf(1.f + e));
  } else if (idx < 327680) {               // W1/W2/W3 A-frags (graph stage)
    int o = idx - 278528;
    int m = o >> 14;
    int oo = o & 16383;
    int i = oo & 7, l = (oo >> 3) & 63, f = oo >> 9;
    int kt = f & 3, rt = f >> 2;
    int g = 16 * rt + (l & 15);
    int k = 32 * kt + 8 * (l >> 4) + i;
    const float* W = (m == 0) ? W1 : (m == 1) ? W2 : W3;
    unsigned short* dst = (unsigned short*)(ws + ((m == 0) ? O_W1APK : (m == 1) ? O_W2APK : O_W3APK));
    dst[oo] = f2bf(W[g * 128 + k]);
  } else if (idx < 328192) {
    int c = idx - 327680;
    ((float*)(ws + O_BIAS0))[c] = bih0[c] + bhh0[c];
  } else {                                 // BIAS1: pre-scaled by gate
    int c = idx - 328192;
    float sc = ((c >> 7) == 2) ? K2 : K1;
    ((float*)(ws + O_BIAS1))[c] = (bih1[c] + bhh1[c]) * sc;
  }
}

// ---------------- LSTM layer 0: 32 rows/block, 16 waves, 32x32 MFMA --------
__global__ __launch_bounds__(1024, 4) void lstm0_k(char* __restrict__ ws, int row_base)
{
  const unsigned short* W0pk = (const unsigned short*)(ws + O_W0PK);
  const unsigned short* xpk = (const unsigned short*)(ws + O_XPK);
  unsigned short* h1 = (unsigned short*)(ws + O_H1);

  int tid = threadIdx.x;
  int Wv = tid >> 6, l = tid & 63, col = l & 31, hi = l >> 5;
  int lrow = blockIdx.x * 32;
  long grow0 = (long)row_base + lrow;

  __shared__ unsigned char hlds[2][8192];  // h state [32 rows][128 u] swizzled
  ((unsigned long long*)hlds[0])[tid] = 0ull;   // zero buffer 0 (8KB)

  bf16x8 Af[10];
#pragma unroll
  for (int kt = 0; kt < 10; kt++)
    Af[kt] = ((const bf16x8*)W0pk)[(Wv * 10 + kt) * 64 + l];

  f32x2 cs01 = {0.f, 0.f}, cs23 = {0.f, 0.f};

  int rd[8];
#pragma unroll
  for (int ks = 0; ks < 8; ks++)
    rd[ks] = col * 256 + ((32 * ks + 16 * hi) ^ ((col & 15) << 4));
  int whp = col * 256 + ((16 * Wv + 8 * hi) ^ ((col & 15) << 4));

  // coalesced h1 bounce: thread -> row pr, 8B col pc8
  int pr = tid >> 5, pc8 = tid & 31;
  int sld = pr * 256 + ((8 * pc8) ^ ((pr & 15) << 4));
  unsigned short* st = h1 + (long)(lrow + pr) * 8192 + 4 * pc8;

  long xbase = (grow0 >> 5) * 8192 + l;
  const bf16x8* xpf = (const bf16x8*)xpk;
  bf16x8 xb0 = xpf[xbase], xb1 = xpf[xbase + 64];
  __syncthreads();

  for (int t = 0; t < 64; t++) {
    const unsigned char* rbuf = hlds[t & 1];
    unsigned char* wbuf = hlds[(t & 1) ^ 1];
    int tn = (t < 63) ? t + 1 : 63;
    bf16x8 xb0n = xpf[xbase + tn * 128];
    bf16x8 xb1n = xpf[xbase + tn * 128 + 64];

    f32x16 acc = (f32x16)0.f;
    __builtin_amdgcn_s_setprio(1);           // T5
#pragma unroll
    for (int ks = 0; ks < 8; ks++) {
      bf16x8 hb = *(const bf16x8*)(rbuf + rd[ks]);
      acc = __builtin_amdgcn_mfma_f32_32x32x16_bf16(Af[ks], hb, acc, 0, 0, 0);
    }
    acc = __builtin_amdgcn_mfma_f32_32x32x16_bf16(Af[8], xb0, acc, 0, 0, 0);
    acc = __builtin_amdgcn_mfma_f32_32x32x16_bf16(Af[9], xb1, acc, 0, 0, 0);
    __builtin_amdgcn_s_setprio(0);

    unsigned pk01 = cell_pair((f32x2){acc[0], acc[4]}, (f32x2){acc[1], acc[5]},
                              (f32x2){acc[2], acc[6]}, (f32x2){acc[3], acc[7]}, cs01);
    unsigned pk23 = cell_pair((f32x2){acc[8], acc[12]}, (f32x2){acc[9], acc[13]},
                              (f32x2){acc[10], acc[14]}, (f32x2){acc[11], acc[15]}, cs23);
    *(unsigned long long*)(wbuf + whp) =
        ((unsigned long long)pk23 << 32) | pk01;
    xb0 = xb0n; xb1 = xb1n;
    __syncthreads();
    // h(t) complete: coalesced global store (8B/thread, 256B contiguous rows)
    *(unsigned long long*)(st + t * 128) =
        *(const unsigned long long*)(hlds[(t & 1) ^ 1] + sld);
  }
}

// ---------------- LSTM layer 1: 32 rows/block, 16 waves, 32x32 MFMA --------
__global__ __launch_bounds__(1024, 4) void lstm1_k(char* __restrict__ ws, int row_base)
{
  const unsigned short* W1pk = (const unsigned short*)(ws + O_W1PK);
  const float* bias1 = (const float*)(ws + O_BIAS1);
  const unsigned short* h1 = (const unsigned short*)(ws + O_H1);
  unsigned short* hTt = (unsigned short*)(ws + O_HTT);

  int tid = threadIdx.x;
  int Wv = tid >> 6, l = tid & 63, col = l & 31, hi = l >> 5;
  int lrow = blockIdx.x * 32;
  long grow0 = (long)row_base + lrow;

  __shared__ unsigned char hlds[2][8192];  // layer-1 h state
  __shared__ unsigned char h1s[2][8192];   // staged h1 input
  ((unsigned long long*)hlds[0])[tid] = 0ull;

  // h1 staging: thread -> row prow, 8B col pc8
  int prow = tid >> 5, pc8 = tid & 31;
  const unsigned short* s0 = h1 + (long)(lrow + prow) * 8192 + 4 * pc8;
  int d0 = prow * 256 + ((8 * pc8) ^ ((prow & 15) << 4));
  *(unsigned long long*)(h1s[0] + d0) = *(const unsigned long long*)s0;  // t=0

  bf16x8 Af[16];
#pragma unroll
  for (int kt = 0; kt < 16; kt++)
    Af[kt] = ((const bf16x8*)W1pk)[(Wv * 16 + kt) * 64 + l];

  int u0 = 8 * Wv + 4 * hi;
  f32x16 bias_c;
#pragma unroll
  for (int r = 0; r < 16; r++)
    bias_c[r] = bias1[(r & 3) * 128 + u0 + (r >> 2)];

  f32x2 cs01 = {0.f, 0.f}, cs23 = {0.f, 0.f};

  int rd[8];
#pragma unroll
  for (int ks = 0; ks < 8; ks++)
    rd[ks] = col * 256 + ((32 * ks + 16 * hi) ^ ((col & 15) << 4));
  int whp = col * 256 + ((16 * Wv + 8 * hi) ^ ((col & 15) << 4));
  __syncthreads();

  for (int t = 0; t < 64; t++) {
    const unsigned char* rbuf = hlds[t & 1];
    unsigned char* wbuf = hlds[(t & 1) ^ 1];
    const unsigned char* h1r = h1s[t & 1];
    unsigned char* h1w = h1s[(t & 1) ^ 1];
    int tn = (t < 63) ? t + 1 : 63;
    unsigned long long pf = *(const unsigned long long*)(s0 + tn * 128);

    f32x16 acc = bias_c;
    __builtin_amdgcn_s_setprio(1);           // T5
#pragma unroll
    for (int ks = 0; ks < 8; ks++) {
      bf16x8 xb = *(const bf16x8*)(h1r + rd[ks]);
      acc = __builtin_amdgcn_mfma_f32_32x32x16_bf16(Af[ks], xb, acc, 0, 0, 0);
    }
#pragma unroll
    for (int ks = 0; ks < 8; ks++) {
      bf16x8 hb = *(const bf16x8*)(rbuf + rd[ks]);
      acc = __builtin_amdgcn_mfma_f32_32x32x16_bf16(Af[8 + ks], hb, acc, 0, 0, 0);
    }
    __builtin_amdgcn_s_setprio(0);

    unsigned pk01 = cell_pair((f32x2){acc[0], acc[4]}, (f32x2){acc[1], acc[5]},
                              (f32x2){acc[2], acc[6]}, (f32x2){acc[3], acc[7]}, cs01);
    unsigned pk23 = cell_pair((f32x2){acc[8], acc[12]}, (f32x2){acc[9], acc[13]},
                              (f32x2){acc[10], acc[14]}, (f32x2){acc[11], acc[15]}, cs23);
    *(unsigned long long*)(wbuf + whp) =
        ((unsigned long long)pk23 << 32) | pk01;
    *(unsigned long long*)(h1w + d0) = pf;
    __syncthreads();
  }

  // peeled epilogue: final h (t=63) lives in hlds[0]; scatter to hTt [b][u][n]
  {
    unsigned long long hp = *(const unsigned long long*)(hlds[0] + whp);
    long grow = grow0 + col;
    long base = ((grow >> 8) * 128) * 256 + (grow & 255);
#pragma unroll
    for (int j = 0; j < 4; j++)
      hTt[base + (long)(u0 + j) * 256] = (unsigned short)((hp >> (16 * j)) & 0xffff);
  }
}

// ---------------- graph stage (unchanged, verified) ------------------------
__global__ __launch_bounds__(256, 2) void g1_kernel(char* __restrict__ ws)
{
  const unsigned short* hTt = (const unsigned short*)(ws + O_HTT);
  const unsigned short* Apk = (const unsigned short*)(ws + O_APK);
  unsigned short* HAt = (unsigned short*)(ws + O_HAT);
  int tid = threadIdx.x, w = tid >> 6, l = tid & 63, lr = l & 15, lq = l >> 4;
  int bi = blockIdx.x;
  int b = bi >> 3, rtp = (bi >> 1) & 3, ch = bi & 1;
  f32x4 acc[2][2];
#pragma unroll
  for (int i = 0; i < 2; i++)
#pragma unroll
    for (int j = 0; j < 2; j++) acc[i][j] = (f32x4){0.f, 0.f, 0.f, 0.f};
  for (int kt = 0; kt < 8; kt++) {
    bf16x8 af[2];
#pragma unroll
    for (int rtl = 0; rtl < 2; rtl++) {
      int rt = rtp * 2 + rtl;
      af[rtl] = *(const bf16x8*)(hTt + (long)(b * 128 + 16 * rt + lr) * 256 + 32 * kt + 8 * lq);
    }
#pragma unroll
    for (int cti = 0; cti < 2; cti++) {
      int ct = w * 4 + ch * 2 + cti;
      bf16x8 bf = ((const bf16x8*)Apk)[(ct * 8 + kt) * 64 + l];
#pragma unroll
      for (int rtl = 0; rtl < 2; rtl++)
        acc[rtl][cti] = __builtin_amdgcn_mfma_f32_16x16x32_bf16(af[rtl], bf, acc[rtl][cti], 0, 0, 0);
    }
  }
#pragma unroll
  for (int rtl = 0; rtl < 2; rtl++)
#pragma unroll
    for (int cti = 0; cti < 2; cti++) {
      int rt = rtp * 2 + rtl, ct = w * 4 + ch * 2 + cti;
      u16x4 pk;
#pragma unroll
      for (int r = 0; r < 4; r++) pk[r] = f2bf(acc[rtl][cti][r]);
      *(u16x4*)(HAt + (long)(b * 256 + 16 * ct + lr) * 128 + 16 * rt + 4 * lq) = pk;
    }
}

__global__ __launch_bounds__(256, 2) void g2_kernel(char* __restrict__ ws)
{
  const unsigned short* HAt = (const unsigned short*)(ws + O_HAT);
  const unsigned short* W1apk = (const unsigned short*)(ws + O_W1APK);
  const unsigned short* W2apk = (const unsigned short*)(ws + O_W2APK);
  unsigned short* W1hAt = (unsigned short*)(ws + O_W1HAT);
  unsigned short* midT = (unsigned short*)(ws + O_MIDT);
  int tid = threadIdx.x, w = tid >> 6, l = tid & 63, lr = l & 15, lq = l >> 4;
  int bi = blockIdx.x;
  int b = bi >> 3, rtp = (bi >> 1) & 3, ch = bi & 1;
  f32x4 a1[2][2], a2[2][2];
#pragma unroll
  for (int i = 0; i < 2; i++)
#pragma unroll
    for (int j = 0; j < 2; j++) { a1[i][j] = (f32x4){0.f,0.f,0.f,0.f}; a2[i][j] = (f32x4){0.f,0.f,0.f,0.f}; }
  for (int kt = 0; kt < 4; kt++) {
    bf16x8 af1[2], af2[2];
#pragma unroll
    for (int rtl = 0; rtl < 2; rtl++) {
      int rt = rtp * 2 + rtl;
      af1[rtl] = ((const bf16x8*)W1apk)[(rt * 4 + kt) * 64 + l];
      af2[rtl] = ((const bf16x8*)W2apk)[(rt * 4 + kt) * 64 + l];
    }
#pragma unroll
    for (int cti = 0; cti < 2; cti++) {
      int ct = w * 4 + ch * 2 + cti;
      bf16x8 bf = *(const bf16x8*)(HAt + (long)(b * 256 + 16 * ct + lr) * 128 + 32 * kt + 8 * lq);
#pragma unroll
      for (int rtl = 0; rtl < 2; rtl++) {
        a1[rtl][cti] = __builtin_amdgcn_mfma_f32_16x16x32_bf16(af1[rtl], bf, a1[rtl][cti], 0, 0, 0);
        a2[rtl][cti] = __builtin_amdgcn_mfma_f32_16x16x32_bf16(af2[rtl], bf, a2[rtl][cti], 0, 0, 0);
      }
    }
  }
#pragma unroll
  for (int rtl = 0; rtl < 2; rtl++)
#pragma unroll
    for (int cti = 0; cti < 2; cti++) {
      int rt = rtp * 2 + rtl, ct = w * 4 + ch * 2 + cti;
      u16x4 p1, p2;
#pragma unroll
      for (int r = 0; r < 4; r++) {
        p1[r] = f2bf(a1[rtl][cti][r]);
        p2[r] = f2bf(fmaxf(a2[rtl][cti][r], 0.f));
      }
      long off = (long)(b * 256 + 16 * ct + lr) * 128 + 16 * rt + 4 * lq;
      *(u16x4*)(W1hAt + off) = p1;
      *(u16x4*)(midT + off) = p2;
    }
}

__global__ __launch_bounds__(256, 2) void g3_kernel(char* __restrict__ ws)
{
  const unsigned short* midT = (const unsigned short*)(ws + O_MIDT);
  const unsigned short* W3apk = (const unsigned short*)(ws + O_W3APK);
  unsigned short* W3r = (unsigned short*)(ws + O_W3R);
  int tid = threadIdx.x, w = tid >> 6, l = tid & 63, lr = l & 15, lq = l >> 4;
  int bi = blockIdx.x;
  int b = bi >> 3, rtp = (bi >> 1) & 3, ch = bi & 1;
  f32x4 acc[2][2];
#pragma unroll
  for (int i = 0; i < 2; i++)
#pragma unroll
    for (int j = 0; j < 2; j++) acc[i][j] = (f32x4){0.f, 0.f, 0.f, 0.f};
  for (int kt = 0; kt < 4; kt++) {
    bf16x8 af[2];
#pragma unroll
    for (int rtl = 0; rtl < 2; rtl++)
      af[rtl] = ((const bf16x8*)W3apk)[((rtp * 2 + rtl) * 4 + kt) * 64 + l];
#pragma unroll
    for (int cti = 0; cti < 2; cti++) {
      int ct = w * 4 + ch * 2 + cti;
      bf16x8 bf = *(const bf16x8*)(midT + (long)(b * 256 + 16 * ct + lr) * 128 + 32 * kt + 8 * lq);
#pragma unroll
      for (int rtl = 0; rtl < 2; rtl++)
        acc[rtl][cti] = __builtin_amdgcn_mfma_f32_16x16x32_bf16(af[rtl], bf, acc[rtl][cti], 0, 0, 0);
    }
  }
#pragma unroll
  for (int rtl = 0; rtl < 2; rtl++)
#pragma unroll
    for (int cti = 0; cti < 2; cti++) {
      int rt = rtp * 2 + rtl, ct = w * 4 + ch * 2 + cti;
#pragma unroll
      for (int r = 0; r < 4; r++)
        W3r[(long)(b * 128 + 16 * rt + 4 * lq + r) * 256 + 16 * ct + lr] = f2bf(acc[rtl][cti][r]);
    }
}

__global__ __launch_bounds__(256, 2) void g4_kernel(char* __restrict__ ws,
    const float* __restrict__ Wfc, float* __restrict__ out)
{
  const unsigned short* W3r = (const unsigned short*)(ws + O_W3R);
  const unsigned short* Apk = (const unsigned short*)(ws + O_APK);
  const unsigned short* W1hAt = (const unsigned short*)(ws + O_W1HAT);
  int tid = threadIdx.x, w = tid >> 6, l = tid & 63, lr = l & 15, lq = l >> 4;
  int bi = blockIdx.x;
  int b = bi >> 2, cq = bi & 3;
  int ct = cq * 4 + w;
  f32x4 acc[8];
#pragma unroll
  for (int i = 0; i < 8; i++) acc[i] = (f32x4){0.f, 0.f, 0.f, 0.f};
  for (int kt = 0; kt < 8; kt++) {
    bf16x8 bfv = ((const bf16x8*)Apk)[(ct * 8 + kt) * 64 + l];
#pragma unroll
    for (int rt = 0; rt < 8; rt++) {
      bf16x8 af = *(const bf16x8*)(W3r + (long)(b * 128 + 16 * rt + lr) * 256 + 32 * kt + 8 * lq);
      acc[rt] = __builtin_amdgcn_mfma_f32_16x16x32_bf16(af, bfv, acc[rt], 0, 0, 0);
    }
  }
  float psum = 0.f;
#pragma unroll
  for (int rt = 0; rt < 8; rt++) {
    float4 wf = *(const float4*)(Wfc + 16 * rt + 4 * lq);
    u16x4 wv = *(const u16x4*)(W1hAt + (long)(b * 256 + 16 * ct + lr) * 128 + 16 * rt + 4 * lq);
    psum += wf.x * (0.1f * acc[rt][0] + 0.9f * bf2f(wv[0]));
    psum += wf.y * (0.1f * acc[rt][1] + 0.9f * bf2f(wv[1]));
    psum += wf.z * (0.1f * acc[rt][2] + 0.9f * bf2f(wv[2]));
    psum += wf.w * (0.1f * acc[rt][3] + 0.9f * bf2f(wv[3]));
  }
  psum += __shfl_xor(psum, 16);
  psum += __shfl_xor(psum, 32);
  if (lq == 0) out[b * 256 + ct * 16 + lr] = __builtin_amdgcn_rcpf(1.f + fexp2(-1.44269504f * psum));
}

// ---------------------------------------------------------------------------
extern "C" void kernel_launch(void* const* d_in, const int* in_sizes, int n_in,
                              void* d_out, int out_size, void* d_ws, size_t ws_size,
                              hipStream_t stream)
{
  const float* x    = (const float*)d_in[0];
  const float* A    = (const float*)d_in[1];
  const float* Wih0 = (const float*)d_in[2];
  const float* Whh0 = (const float*)d_in[3];
  const float* bih0 = (const float*)d_in[4];
  const float* bhh0 = (const float*)d_in[5];
  const float* Wih1 = (const float*)d_in[6];
  const float* Whh1 = (const float*)d_in[7];
  const float* bih1 = (const float*)d_in[8];
  const float* bhh1 = (const float*)d_in[9];
  const float* W1   = (const float*)d_in[10];
  const float* W2   = (const float*)d_in[11];
  const float* W3   = (const float*)d_in[12];
  const float* Wfc  = (const float*)d_in[13];
  char* ws = (char*)d_ws;

  prep_all<<<(PREPALL_TOT + 255) / 256, 256, 0, stream>>>(
      x, A, Wih0, Whh0, bih0, bhh0, Wih1, Whh1, bih1, bhh1, W1, W2, W3, ws);

  size_t need_full = (size_t)O_H1 + 134217728u;  // 8192-row h1
  size_t need_half = (size_t)O_H1 + 67108864u;   // 4096-row h1
  if (ws_size >= need_full) {
    lstm0_k<<<256, 1024, 0, stream>>>(ws, 0);
    lstm1_k<<<256, 1024, 0, stream>>>(ws, 0);
  } else if (ws_size >= need_half) {
    for (int c = 0; c < 2; c++) {
      lstm0_k<<<128, 1024, 0, stream>>>(ws, c * 4096);
      lstm1_k<<<128, 1024, 0, stream>>>(ws, c * 4096);
    }
  } else {
    for (int c = 0; c < 4; c++) {
      lstm0_k<<<64, 1024, 0, stream>>>(ws, c * 2048);
      lstm1_k<<<64, 1024, 0, stream>>>(ws, c * 2048);
    }
  }

  g1_kernel<<<256, 256, 0, stream>>>(ws);
  g2_kernel<<<256, 256, 0, stream>>>(ws);
  g3_kernel<<<256, 256, 0, stream>>>(ws);
  g4_kernel<<<128, 256, 0, stream>>>(ws, Wfc, (float*)d_out);
}